// Round 7
// baseline (40.276 us; speedup 1.0000x reference)
//
#include <hip/hip_runtime.h>

// Problem constants: V=50000, F=100000, H=W=256, K=1, B=4, J=256
#define NPIX  65536
#define BB    4
#define JJ    256

// Output layout (concatenated flat, fp32):
//   colors  : (B,H,W,3)  base 0
//   diffuse : (B,H,W,3)  base 786432
//   texels  : (1,H,W,3)  base 1572864
//   normals : (B,H,W,3)  base 1769472

struct F3 { float x, y, z; };
struct I3 { int x, y, z; };

// Grid: 2048 blocks x 256 threads (8 blocks/CU, 32 waves/CU).
//   b     = blockIdx.x >> 9   (batch, block-uniform)
//   pbase = (blockIdx.x & 511) * 128
// Phase 0: stage this batch's 256 lights into LDS as [j][8] f32
//          (LDS is in-order lgkmcnt -> compiler software-pipelines ds_read,
//           unlike SMEM's lgkmcnt(0) full drain per unroll group).
// Phase 1: wave w, lanes 0..31 gather+normalize pixels w*32..w*32+31 -> LDS
//          (gather balanced across all 4 waves/SIMDs).
// Phase 2: wave w handles light quarter w (uniform LDS broadcast reads),
//          2 pixels/thread x 64 lights.
// Phase 3: merge quarters via LDS, threads 0..127 write colors/diffuse.
__global__ __launch_bounds__(256, 8) void shade_kernel(
    const int*   __restrict__ p2f,    // (1,H,W,1) int32
    const float* __restrict__ bary,   // (1,H,W,1,3)
    const int*   __restrict__ faces,  // (F,3)
    const float* __restrict__ vnorm,  // (V,3)
    const float* __restrict__ dirs,   // (B,J,3)
    const float* __restrict__ env,    // (B,J,3)
    const float* __restrict__ tex,    // (1,H,W,3)
    float*       __restrict__ out)
{
    const int b     = blockIdx.x >> 9;                 // batch (block-uniform)
    const int pbase = (blockIdx.x & 511) << 7;         // first pixel of block
    const int t     = threadIdx.x;
    const int i     = t & 63;                          // lane
    const int w     = t >> 6;                          // wave id 0..3

    __shared__ float4 llds[JJ][2];                     // 8 KB lights
    __shared__ float4 nlds[128];                       // 2 KB normals
    __shared__ float  part[4][128][3];                 // 6 KB partials

    const F3* __restrict__ bary3  = (const F3*)bary;
    const I3* __restrict__ faces3 = (const I3*)faces;
    const F3* __restrict__ vn3    = (const F3*)vnorm;
    const F3* __restrict__ tex3   = (const F3*)tex;

    // ---- Phase 0: stage lights (1 light/thread, coalesced) ----
    {
        const F3 d = ((const F3*)dirs)[b * JJ + t];
        const F3 e = ((const F3*)env )[b * JJ + t];
        llds[t][0] = make_float4(d.x, d.y, d.z, e.x);
        llds[t][1] = make_float4(e.y, e.z, 0.f, 0.f);
    }

    // ---- Phase 1: gather + normalize (wave w -> pixels w*32..w*32+31) ----
    if (i < 32) {
        const int lp = (w << 5) + i;                   // local pixel 0..127
        const int p  = pbase + lp;
        const int f  = p2f[p];
        const I3 vv = faces3[f];
        const F3 bc = bary3[p];
        const F3 a0 = vn3[vv.x];
        const F3 a1 = vn3[vv.y];
        const F3 a2 = vn3[vv.z];
        float nx = bc.x*a0.x + bc.y*a1.x + bc.z*a2.x;
        float ny = bc.x*a0.y + bc.y*a1.y + bc.z*a2.y;
        float nz = bc.x*a0.z + bc.y*a1.z + bc.z*a2.z;
        const float inv = 1.0f / fmaxf(sqrtf(nx*nx + ny*ny + nz*nz), 1e-6f);
        nx *= inv; ny *= inv; nz *= inv;
        nlds[lp] = make_float4(nx, ny, nz, 0.f);

        // normals output (this block's batch copy)
        float* __restrict__ nor = out + (3*BB*NPIX*2 + 3*NPIX);
        const int o = 3*(b*NPIX + p);
        nor[o+0] = nx; nor[o+1] = ny; nor[o+2] = nz;

        // texels passthrough (batch-0 blocks cover all pixels)
        if (b == 0) {
            const F3 tv = tex3[p];
            float* __restrict__ tx = out + 3*BB*NPIX*2;
            tx[3*p+0] = tv.x; tx[3*p+1] = tv.y; tx[3*p+2] = tv.z;
        }
    }
    __syncthreads();

    // ---- Phase 2: 2 pixels/thread, 64 lights from LDS (broadcast reads) ----
    const float4 n0 = nlds[i];
    const float4 n1 = nlds[64 + i];

    float a0r=0.f, a0g=0.f, a0b=0.f, a1r=0.f, a1g=0.f, a1b=0.f;
    const int jb = w << 6;                             // light-quarter base

    #pragma unroll 16
    for (int j = 0; j < 64; ++j) {
        const float4 q0 = llds[jb + j][0];             // dx,dy,dz,er
        const float4 q1 = llds[jb + j][1];             // eg,eb,-,-
        float w0 = fmaf(n0.z, q0.z, fmaf(n0.y, q0.y, n0.x*q0.x));
        float w1 = fmaf(n1.z, q0.z, fmaf(n1.y, q0.y, n1.x*q0.x));
        w0 = fminf(fmaxf(w0, 0.f), 1.f);               // v_med3_f32
        w1 = fminf(fmaxf(w1, 0.f), 1.f);
        a0r = fmaf(q0.w, w0, a0r); a0g = fmaf(q1.x, w0, a0g); a0b = fmaf(q1.y, w0, a0b);
        a1r = fmaf(q0.w, w1, a1r); a1g = fmaf(q1.x, w1, a1g); a1b = fmaf(q1.y, w1, a1b);
    }

    // ---- Phase 3: partials -> LDS, merge, store ----
    part[w][i][0]      = a0r; part[w][i][1]      = a0g; part[w][i][2]      = a0b;
    part[w][64+i][0]   = a1r; part[w][64+i][1]   = a1g; part[w][64+i][2]   = a1b;
    __syncthreads();

    if (t < 128) {
        const int p = pbase + t;
        const float sr = part[0][t][0]+part[1][t][0]+part[2][t][0]+part[3][t][0];
        const float sg = part[0][t][1]+part[1][t][1]+part[2][t][1]+part[3][t][1];
        const float sb = part[0][t][2]+part[1][t][2]+part[2][t][2]+part[3][t][2];

        const F3 tv = tex3[p];
        const int o = 3*(b*NPIX + p);
        out[o+0] = sr*tv.x; out[o+1] = sg*tv.y; out[o+2] = sb*tv.z;

        float* __restrict__ dif = out + 3*BB*NPIX;
        dif[o+0] = sr; dif[o+1] = sg; dif[o+2] = sb;
    }
}

extern "C" void kernel_launch(void* const* d_in, const int* in_sizes, int n_in,
                              void* d_out, int out_size, void* d_ws, size_t ws_size,
                              hipStream_t stream) {
    const int*   p2f   = (const int*)  d_in[0];
    const float* bary  = (const float*)d_in[1];
    const int*   faces = (const int*)  d_in[2];
    // d_in[3] = verts (unused)
    const float* vnorm = (const float*)d_in[4];
    const float* dirs  = (const float*)d_in[5];
    const float* env   = (const float*)d_in[6];
    const float* tex   = (const float*)d_in[7];
    float* out = (float*)d_out;

    const int grid = BB * (NPIX / 128);   // 4 * 512 = 2048 blocks
    shade_kernel<<<grid, 256, 0, stream>>>(
        p2f, bary, faces, vnorm, dirs, env, tex, out);
}

// Round 8
// 22.864 us; speedup vs baseline: 1.7616x; 1.7616x over previous
//
#include <hip/hip_runtime.h>

// Problem constants: V=50000, F=100000, H=W=256, K=1, B=4, J=256
#define NPIX  65536
#define BB    4
#define JJ    256

// Output layout (concatenated flat, fp32):
//   colors  : (B,H,W,3)  base 0
//   diffuse : (B,H,W,3)  base 786432
//   texels  : (1,H,W,3)  base 1572864
//   normals : (B,H,W,3)  base 1769472

struct F3 { float x, y, z; };
struct I3 { int x, y, z; };

// Grid: 1024 blocks x 512 threads (8 waves/block; 8 waves/SIMD occupancy).
//   b     = blockIdx.x >> 8   (batch, block-uniform)
//   pbase = (blockIdx.x & 255) * 256
// Wave w owns light slice [w*32, w*32+32); lane j<32 holds light j in 6 VGPRs.
// Inner loop: v_readlane (const lane) -> SGPR broadcast; ZERO memory ops.
// Each lane computes 4 pixels; 8 slice-partials merged via LDS.
__global__ __launch_bounds__(512, 8) void shade_kernel(
    const int*   __restrict__ p2f,    // (1,H,W,1) int32
    const float* __restrict__ bary,   // (1,H,W,1,3)
    const int*   __restrict__ faces,  // (F,3)
    const float* __restrict__ vnorm,  // (V,3)
    const float* __restrict__ dirs,   // (B,J,3)
    const float* __restrict__ env,    // (B,J,3)
    const float* __restrict__ tex,    // (1,H,W,3)
    float*       __restrict__ out)
{
    const int b     = blockIdx.x >> 8;                 // batch (block-uniform)
    const int pbase = (blockIdx.x & 255) << 8;         // first pixel (256/block)
    const int t     = threadIdx.x;
    const int lane  = t & 63;
    const int w     = t >> 6;                          // wave id 0..7

    __shared__ float4 nlds[256];                       // 4 KB normals
    __shared__ float4 part4[8][256];                   // 32 KB partials

    const F3* __restrict__ bary3  = (const F3*)bary;
    const I3* __restrict__ faces3 = (const I3*)faces;
    const F3* __restrict__ vn3    = (const F3*)vnorm;
    const F3* __restrict__ tex3   = (const F3*)tex;

    // ---- Phase L: this wave's 32 lights -> VGPRs (lane j holds light j) ----
    float ldx = 0.f, ldy = 0.f, ldz = 0.f, ler = 0.f, leg = 0.f, leb = 0.f;
    if (lane < 32) {
        const int j = b * JJ + (w << 5) + lane;
        const F3 d = ((const F3*)dirs)[j];
        const F3 e = ((const F3*)env )[j];
        ldx = d.x; ldy = d.y; ldz = d.z; ler = e.x; leg = e.y; leb = e.z;
    }

    // ---- Phase G: gather + normalize (threads 0..255, once per pixel) ----
    if (t < 256) {
        const int p = pbase + t;
        const int f = p2f[p];
        const I3 vv = faces3[f];
        const F3 bc = bary3[p];
        const F3 a0 = vn3[vv.x];
        const F3 a1 = vn3[vv.y];
        const F3 a2 = vn3[vv.z];
        float nx = bc.x*a0.x + bc.y*a1.x + bc.z*a2.x;
        float ny = bc.x*a0.y + bc.y*a1.y + bc.z*a2.y;
        float nz = bc.x*a0.z + bc.y*a1.z + bc.z*a2.z;
        const float inv = 1.0f / fmaxf(sqrtf(nx*nx + ny*ny + nz*nz), 1e-6f);
        nx *= inv; ny *= inv; nz *= inv;
        nlds[t] = make_float4(nx, ny, nz, 0.f);

        // normals output (this block's batch copy)
        float* __restrict__ nor = out + (3*BB*NPIX*2 + 3*NPIX);
        const int o = 3*(b*NPIX + p);
        nor[o+0] = nx; nor[o+1] = ny; nor[o+2] = nz;

        // texels passthrough (batch-0 blocks cover all pixels)
        if (b == 0) {
            const F3 tv = tex3[p];
            float* __restrict__ tx = out + 3*BB*NPIX*2;
            tx[3*p+0] = tv.x; tx[3*p+1] = tv.y; tx[3*p+2] = tv.z;
        }
    }
    __syncthreads();

    // ---- Phase J: 4 pixels/lane x 32 lights; inner loop has NO memory ops ----
    float nX[4], nY[4], nZ[4], aR[4], aG[4], aB[4];
    #pragma unroll
    for (int k = 0; k < 4; ++k) {
        const float4 n = nlds[(k << 6) + lane];
        nX[k] = n.x; nY[k] = n.y; nZ[k] = n.z;
        aR[k] = 0.f; aG[k] = 0.f; aB[k] = 0.f;
    }

    #pragma unroll
    for (int j = 0; j < 32; ++j) {
        const float dx = __int_as_float(__builtin_amdgcn_readlane(__float_as_int(ldx), j));
        const float dy = __int_as_float(__builtin_amdgcn_readlane(__float_as_int(ldy), j));
        const float dz = __int_as_float(__builtin_amdgcn_readlane(__float_as_int(ldz), j));
        const float er = __int_as_float(__builtin_amdgcn_readlane(__float_as_int(ler), j));
        const float eg = __int_as_float(__builtin_amdgcn_readlane(__float_as_int(leg), j));
        const float eb = __int_as_float(__builtin_amdgcn_readlane(__float_as_int(leb), j));
        #pragma unroll
        for (int k = 0; k < 4; ++k) {
            float wgt = fmaf(nZ[k], dz, fmaf(nY[k], dy, nX[k]*dx));
            wgt = fminf(fmaxf(wgt, 0.f), 1.f);         // v_med3_f32
            aR[k] = fmaf(er, wgt, aR[k]);
            aG[k] = fmaf(eg, wgt, aG[k]);
            aB[k] = fmaf(eb, wgt, aB[k]);
        }
    }

    // ---- Phase M: slice partials -> LDS ----
    #pragma unroll
    for (int k = 0; k < 4; ++k)
        part4[w][(k << 6) + lane] = make_float4(aR[k], aG[k], aB[k], 0.f);
    __syncthreads();

    // ---- Phase C: threads 0..255 reduce 8 slices, write colors+diffuse ----
    if (t < 256) {
        float4 s = part4[0][t];
        #pragma unroll
        for (int q = 1; q < 8; ++q) {
            const float4 v = part4[q][t];
            s.x += v.x; s.y += v.y; s.z += v.z;
        }
        const int p = pbase + t;
        const F3 tv = tex3[p];
        const int o = 3*(b*NPIX + p);
        out[o+0] = s.x*tv.x; out[o+1] = s.y*tv.y; out[o+2] = s.z*tv.z;

        float* __restrict__ dif = out + 3*BB*NPIX;
        dif[o+0] = s.x; dif[o+1] = s.y; dif[o+2] = s.z;
    }
}

extern "C" void kernel_launch(void* const* d_in, const int* in_sizes, int n_in,
                              void* d_out, int out_size, void* d_ws, size_t ws_size,
                              hipStream_t stream) {
    const int*   p2f   = (const int*)  d_in[0];
    const float* bary  = (const float*)d_in[1];
    const int*   faces = (const int*)  d_in[2];
    // d_in[3] = verts (unused)
    const float* vnorm = (const float*)d_in[4];
    const float* dirs  = (const float*)d_in[5];
    const float* env   = (const float*)d_in[6];
    const float* tex   = (const float*)d_in[7];
    float* out = (float*)d_out;

    const int grid = BB * (NPIX / 256);   // 4 * 256 = 1024 blocks
    shade_kernel<<<grid, 512, 0, stream>>>(
        p2f, bary, faces, vnorm, dirs, env, tex, out);
}